// Round 1
// baseline (121.880 us; speedup 1.0000x reference)
//
#include <hip/hip_runtime.h>

// Spatial transformer: batched dense-displacement trilinear warp.
// vol: [B=2, D=128, H=192, W=192, C=1] f32
// trf: [B=2, D=128, H=192, W=192, 3]  f32 (displacement along D,H,W)
// out: [B=2, D=128, H=192, W=192, 1]  f32

#define BD 128
#define BH 192
#define BW 192
#define DHW (BD * BH * BW)
#define NBATCH 2

__global__ __launch_bounds__(256) void st_warp_kernel(
    const float* __restrict__ vol,
    const float* __restrict__ trf,
    float* __restrict__ out)
{
    const int g = blockIdx.x * blockDim.x + threadIdx.x;  // group of 4 x-voxels
    const int NG = NBATCH * DHW / 4;
    if (g >= NG) return;

    // decompose group index -> (b, z, y, x4)
    int x4 = g % (BW / 4);
    int t  = g / (BW / 4);
    int y  = t % BH;
    int t2 = t / BH;
    int z  = t2 % BD;
    int b  = t2 / BD;

    // 3 float4 loads = 12 floats = displacement (dz,dy,dx) for 4 voxels
    const float4* trf4 = (const float4*)trf;
    float4 ta = trf4[(size_t)g * 3 + 0];
    float4 tb = trf4[(size_t)g * 3 + 1];
    float4 tc = trf4[(size_t)g * 3 + 2];

    const float dzs[4] = {ta.x, ta.w, tb.z, tc.y};
    const float dys[4] = {ta.y, tb.x, tb.w, tc.z};
    const float dxs[4] = {ta.z, tb.y, tc.x, tc.w};

    const float* volb = vol + (size_t)b * DHW;

    float res[4];
#pragma unroll
    for (int j = 0; j < 4; ++j) {
        // absolute sample coords, edge-clamped (voxelmorph interpn fill=None)
        float cz = fminf(fmaxf((float)z + dzs[j], 0.0f), (float)(BD - 1));
        float cy = fminf(fmaxf((float)y + dys[j], 0.0f), (float)(BH - 1));
        float cx = fminf(fmaxf((float)(x4 * 4 + j) + dxs[j], 0.0f), (float)(BW - 1));

        float fz = floorf(cz), fy = floorf(cy), fx = floorf(cx);
        int z0 = (int)fz, y0 = (int)fy, x0 = (int)fx;
        int z1 = min(z0 + 1, BD - 1);
        int y1 = min(y0 + 1, BH - 1);
        int x1 = min(x0 + 1, BW - 1);
        float wz = cz - fz, wy = cy - fy, wx = cx - fx;

        const float* p00 = volb + ((size_t)z0 * BH + y0) * BW;
        const float* p01 = volb + ((size_t)z0 * BH + y1) * BW;
        const float* p10 = volb + ((size_t)z1 * BH + y0) * BW;
        const float* p11 = volb + ((size_t)z1 * BH + y1) * BW;

        float v000 = p00[x0], v001 = p00[x1];
        float v010 = p01[x0], v011 = p01[x1];
        float v100 = p10[x0], v101 = p10[x1];
        float v110 = p11[x0], v111 = p11[x1];

        float c00 = v000 + wx * (v001 - v000);
        float c01 = v010 + wx * (v011 - v010);
        float c10 = v100 + wx * (v101 - v100);
        float c11 = v110 + wx * (v111 - v110);
        float c0  = c00 + wy * (c01 - c00);
        float c1  = c10 + wy * (c11 - c10);
        res[j]    = c0 + wz * (c1 - c0);
    }

    float4 r = make_float4(res[0], res[1], res[2], res[3]);
    ((float4*)out)[g] = r;
}

extern "C" void kernel_launch(void* const* d_in, const int* in_sizes, int n_in,
                              void* d_out, int out_size, void* d_ws, size_t ws_size,
                              hipStream_t stream) {
    const float* vol = (const float*)d_in[0];
    const float* trf = (const float*)d_in[1];
    float* out = (float*)d_out;

    const int NG = NBATCH * DHW / 4;  // 2,359,296 groups of 4 voxels
    dim3 block(256);
    dim3 grid((NG + 255) / 256);
    st_warp_kernel<<<grid, block, 0, stream>>>(vol, trf, out);
}

// Round 3
// 94.272 us; speedup vs baseline: 1.2929x; 1.2929x over previous
//
#include <hip/hip_runtime.h>

// Spatial transformer: batched dense-displacement trilinear warp.
// vol: [B=2, D=128, H=192, W=192, 1] f32
// trf: [B=2, D=128, H=192, W=192, 3] f32 (displacement along z,y,x)
// out: [B=2, D=128, H=192, W=192, 1] f32

#define BD 128
#define BH 192
#define BW 192
#define DHW (BD * BH * BW)
#define NBATCH 2
#define NG (NBATCH * DHW / 4)   // 2,359,296 groups of 4 x-voxels
#define NBLK (NG / 256)         // 9216 blocks (exact, % 8 == 0)
#define NXCD 8

// native clang vector type: accepted by __builtin_nontemporal_load/store
typedef float f4v __attribute__((ext_vector_type(4)));

// 4-byte-aligned float pair: lets the compiler emit global_load_dwordx2 at
// arbitrary float offsets (gfx9+ unaligned-access-mode handles 4B alignment).
struct __attribute__((aligned(4))) f2 { float x, y; };

__global__ __launch_bounds__(256) void st_warp_kernel(
    const float* __restrict__ vol,
    const float* __restrict__ trf,
    float* __restrict__ out)
{
    // XCD-chunked swizzle: blocks round-robin across the 8 XCDs, so give XCD i
    // the contiguous range [i*NBLK/8, (i+1)*NBLK/8) -> each XCD's private 4MB
    // L2 caches a distinct ~2.4MB z-slab of vol instead of 8x-replicating the
    // same window. 9216 % 8 == 0 -> bijective.
    const int bid = blockIdx.x;
    const int swz = (bid % NXCD) * (NBLK / NXCD) + bid / NXCD;
    const int g = swz * 256 + (int)threadIdx.x;

    // decompose -> (b, z, y, x4)
    const int x4 = g % (BW / 4);
    const int t  = g / (BW / 4);
    const int y  = t % BH;
    const int t2 = t / BH;
    const int z  = t2 % BD;
    const int b  = t2 / BD;

    // streaming trf read: non-temporal so the 113MB stream doesn't evict vol
    const f4v* trf4 = (const f4v*)trf;
    const f4v ta = __builtin_nontemporal_load(&trf4[(size_t)g * 3 + 0]);
    const f4v tb = __builtin_nontemporal_load(&trf4[(size_t)g * 3 + 1]);
    const f4v tc = __builtin_nontemporal_load(&trf4[(size_t)g * 3 + 2]);

    const float dzs[4] = {ta.x, ta.w, tb.z, tc.y};
    const float dys[4] = {ta.y, tb.x, tb.w, tc.z};
    const float dxs[4] = {ta.z, tb.y, tc.x, tc.w};

    // ---- phase 1: all addresses + weights (no loads yet) ----
    unsigned int offs[4][4];
    float wxs[4], wys[4], wzs[4];
    int xlo[4];  // x0 < BW-1 ? (select low element of the pair)
#pragma unroll
    for (int j = 0; j < 4; ++j) {
        float cz = fminf(fmaxf((float)z + dzs[j], 0.0f), (float)(BD - 1));
        float cy = fminf(fmaxf((float)y + dys[j], 0.0f), (float)(BH - 1));
        float cx = fminf(fmaxf((float)(x4 * 4 + j) + dxs[j], 0.0f), (float)(BW - 1));
        float fz = floorf(cz), fy = floorf(cy), fx = floorf(cx);
        int z0 = (int)fz, y0 = (int)fy, x0 = (int)fx;
        int z1 = min(z0 + 1, BD - 1);
        int y1 = min(y0 + 1, BH - 1);
        int xa = min(x0, BW - 2);          // pair base; dup-select handles x0==191
        wzs[j] = cz - fz; wys[j] = cy - fy; wxs[j] = cx - fx;
        xlo[j] = (x0 < BW - 1);
        offs[j][0] = (unsigned)((z0 * BH + y0) * BW + xa);
        offs[j][1] = (unsigned)((z0 * BH + y1) * BW + xa);
        offs[j][2] = (unsigned)((z1 * BH + y0) * BW + xa);
        offs[j][3] = (unsigned)((z1 * BH + y1) * BW + xa);
    }

    // ---- phase 2: issue all 16 dwordx2 gathers (one grouped vmcnt wait) ----
    const float* base = vol + (size_t)b * DHW;
    f2 v[4][4];
#pragma unroll
    for (int j = 0; j < 4; ++j) {
#pragma unroll
        for (int r = 0; r < 4; ++r) {
            v[j][r] = *(const f2*)(base + offs[j][r]);
        }
    }

    // ---- phase 3: all math ----
    float res[4];
#pragma unroll
    for (int j = 0; j < 4; ++j) {
        const float wx = wxs[j], wy = wys[j], wz = wzs[j];
        float a00 = xlo[j] ? v[j][0].x : v[j][0].y;
        float a01 = xlo[j] ? v[j][1].x : v[j][1].y;
        float a10 = xlo[j] ? v[j][2].x : v[j][2].y;
        float a11 = xlo[j] ? v[j][3].x : v[j][3].y;
        float c00 = a00 + wx * (v[j][0].y - a00);  // (z0,y0)
        float c01 = a01 + wx * (v[j][1].y - a01);  // (z0,y1)
        float c10 = a10 + wx * (v[j][2].y - a10);  // (z1,y0)
        float c11 = a11 + wx * (v[j][3].y - a11);  // (z1,y1)
        float c0  = c00 + wy * (c01 - c00);
        float c1  = c10 + wy * (c11 - c10);
        res[j]    = c0 + wz * (c1 - c0);
    }

    f4v r = {res[0], res[1], res[2], res[3]};
    __builtin_nontemporal_store(r, &((f4v*)out)[g]);
}

extern "C" void kernel_launch(void* const* d_in, const int* in_sizes, int n_in,
                              void* d_out, int out_size, void* d_ws, size_t ws_size,
                              hipStream_t stream) {
    const float* vol = (const float*)d_in[0];
    const float* trf = (const float*)d_in[1];
    float* out = (float*)d_out;

    st_warp_kernel<<<dim3(NBLK), dim3(256), 0, stream>>>(vol, trf, out);
}

// Round 4
// 50.890 us; speedup vs baseline: 2.3949x; 1.8524x over previous
//
#include <hip/hip_runtime.h>
#include <stdint.h>

// Spatial transformer: batched dense-displacement trilinear warp, LDS-staged.
// vol: [B=2, D=128, H=192, W=192, 1] f32
// trf: [B=2, D=128, H=192, W=192, 3] f32 (displacement along z,y,x)
// out: [B=2, D=128, H=192, W=192, 1] f32

#define BD 128
#define BH 192
#define BW 192
#define DHW (BD*BH*BW)
#define NB 2

// output tile per block: 64 x * 8 y * 4 z = 2048 voxels, 256 thr * 8 vox
#define TX 64
#define TY 8
#define TZ 4
#define NTX (BW/TX)                 // 3
#define NTY (BH/TY)                 // 24
#define NTZ (BD/TZ)                 // 32
#define NBLK (NTX*NTY*NTZ*NB)       // 4608  (% 8 == 0)
#define NXCD 8

// staged window (floats): x 72 [tx-4..tx+67], y 15 [ty-3..ty+11], z 12 [tz-4..tz+7]
// membership is TESTED exactly per sample; misses take the global fallback.
#define SXW 72
#define SYW 15
#define SZW 12
#define SROWS (SYW*SZW)             // 180 rows
#define SF4ROW (SXW/4)              // 18 float4 per row
#define SF4 (SROWS*SF4ROW)          // 3240 float4 staged
#define LDSF (SXW*SROWS)            // 12960 floats = 51840 B -> 3 blocks/CU

typedef float f4v __attribute__((ext_vector_type(4)));

__global__ __launch_bounds__(256) void st_warp_kernel(
    const float* __restrict__ vol,
    const float* __restrict__ trf,
    float* __restrict__ out)
{
    __shared__ __align__(16) float lds[LDSF + 4];   // +pad (x0==191 reads lds[i+1])

    // XCD-chunked swizzle: each XCD gets a contiguous chunk of 576 blocks
    const int bid = blockIdx.x;
    const int swz = (bid % NXCD) * (NBLK / NXCD) + bid / NXCD;
    int tmp = swz;
    const int txi = tmp % NTX; tmp /= NTX;
    const int tyi = tmp % NTY; tmp /= NTY;
    const int tzi = tmp % NTZ; tmp /= NTZ;
    const int b   = tmp;
    const int tx = txi*TX, ty = tyi*TY, tz = tzi*TZ;

    // staged window origin (sx stays 4-aligned: tx-4 in {-4,60,124} -> {0,60,120})
    const int sx = min(max(tx - 4, 0), BW - SXW);
    const int sy = min(max(ty - 3, 0), BH - SYW);
    const int sz = min(max(tz - 4, 0), BD - SZW);

    const int tid  = (int)threadIdx.x;
    const int lane = tid & 63;
    const int w    = tid >> 6;
    const int seg  = lane >> 4;   // row-within-window-chunk
    const int col  = lane & 15;

    // ---------- phase A: trf bounce (coalesced load -> LDS scratch -> regs) ----------
    // tile has 32 (y,z) rows of 64 x-voxels = 48 float4 of trf each.
    // wave w, batch i covers rows [16i+4w, 16i+4w+4). Loads are 16-lane contiguous.
    const f4v* trf4 = (const f4v*)trf;
    f4v* sc = (f4v*)lds;                       // scratch overlay (consumed before staging)
    const int scb = w*196 + seg*49;            // 49-f4 row pitch breaks bank alignment
    f4v tA[2], tB[2], tC[2];
#pragma unroll
    for (int i = 0; i < 2; ++i) {
        const int r  = 16*i + 4*w + seg;       // tile row 0..31
        const int gy = ty + (r & 7);
        const int gz = tz + (r >> 3);
        const int rowf4 = (((b*BD + gz)*BH + gy)*BW + tx) / 4 * 3;
        f4v v0 = __builtin_nontemporal_load(&trf4[rowf4 + 0*16 + col]);
        f4v v1 = __builtin_nontemporal_load(&trf4[rowf4 + 1*16 + col]);
        f4v v2 = __builtin_nontemporal_load(&trf4[rowf4 + 2*16 + col]);
        sc[scb + 0*16 + col] = v0;
        sc[scb + 1*16 + col] = v1;
        sc[scb + 2*16 + col] = v2;
        asm volatile("s_waitcnt lgkmcnt(0)" ::: "memory");
        tA[i] = sc[scb + col*3 + 0];           // this thread's 12 floats (4 voxels x 3)
        tB[i] = sc[scb + col*3 + 1];
        tC[i] = sc[scb + col*3 + 2];
        asm volatile("s_waitcnt lgkmcnt(0)" ::: "memory");  // reads done before overwrite
    }
    __syncthreads();                            // all waves done with scratch

    // ---------- phase B: stage vol window -> LDS via global_load_lds (16B) ----------
    const float* volb = vol + (size_t)b * DHW;
#pragma unroll
    for (int it = 0; it < 13; ++it) {
        const int f = tid + it*256;
        if (f < SF4) {
            const int r  = f / SF4ROW;          // staged row
            const int c  = f - r*SF4ROW;
            const int zi = r / SYW;
            const int yi = r - zi*SYW;
            const float* g = volb + ((size_t)((sz+zi)*BH + (sy+yi)))*BW + sx + c*4;
            __builtin_amdgcn_global_load_lds(
                (const __attribute__((address_space(1))) void*)g,
                (__attribute__((address_space(3))) void*)&lds[f*4],
                16, 0, 0);
        }
    }
    if (tid == 0) lds[LDSF] = 0.0f;             // finite pad for the x==191 corner
    __syncthreads();                            // drains vmcnt + lgkmcnt

    // ---------- phase C: sample 8 voxels from LDS (rare global fallback) ----------
#pragma unroll
    for (int i = 0; i < 2; ++i) {
        const float dzs[4] = {tA[i].x, tA[i].w, tB[i].z, tC[i].y};
        const float dys[4] = {tA[i].y, tB[i].x, tB[i].w, tC[i].z};
        const float dxs[4] = {tA[i].z, tB[i].y, tC[i].x, tC[i].w};
        const int gi = i*256 + tid;
        const int xg = gi & 15;
        const int yb = (gi >> 4) & 7;
        const int zb = gi >> 7;
        const int Y  = ty + yb;
        const int Z  = tz + zb;
        const int Xb = tx + xg*4;
        float res[4];
#pragma unroll
        for (int jj = 0; jj < 4; ++jj) {
            float cz = fminf(fmaxf((float)Z + dzs[jj], 0.f), (float)(BD-1));
            float cy = fminf(fmaxf((float)Y + dys[jj], 0.f), (float)(BH-1));
            float cx = fminf(fmaxf((float)(Xb+jj) + dxs[jj], 0.f), (float)(BW-1));
            float fz = floorf(cz), fy = floorf(cy), fx = floorf(cx);
            int z0 = (int)fz, y0 = (int)fy, x0 = (int)fx;
            int z1 = min(z0+1, BD-1);
            int y1 = min(y0+1, BH-1);
            int x1 = min(x0+1, BW-1);
            float wz = cz - fz, wy = cy - fy, wx = cx - fx;
            float v000,v001,v010,v011,v100,v101,v110,v111;
            bool inwin = (x0 >= sx) & (x1 <= sx+SXW-1) & (y0 >= sy) & (y1 <= sy+SYW-1)
                       & (z0 >= sz) & (z1 <= sz+SZW-1);
            if (inwin) {
                const int zi0 = z0 - sz, zi1 = z1 - sz;
                const int yi0 = y0 - sy, yi1 = y1 - sy;
                const int xi  = x0 - sx;
                const int i00 = (zi0*SYW + yi0)*SXW + xi;
                const int i01 = (zi0*SYW + yi1)*SXW + xi;
                const int i10 = (zi1*SYW + yi0)*SXW + xi;
                const int i11 = (zi1*SYW + yi1)*SXW + xi;
                // x0==x1 (==191) reads a stray lds word at +1, but wx==0 and it is finite
                v000 = lds[i00]; v001 = lds[i00+1];
                v010 = lds[i01]; v011 = lds[i01+1];
                v100 = lds[i10]; v101 = lds[i10+1];
                v110 = lds[i11]; v111 = lds[i11+1];
            } else {
                const float* p00 = volb + ((size_t)z0*BH + y0)*BW;
                const float* p01 = volb + ((size_t)z0*BH + y1)*BW;
                const float* p10 = volb + ((size_t)z1*BH + y0)*BW;
                const float* p11 = volb + ((size_t)z1*BH + y1)*BW;
                v000 = p00[x0]; v001 = p00[x1];
                v010 = p01[x0]; v011 = p01[x1];
                v100 = p10[x0]; v101 = p10[x1];
                v110 = p11[x0]; v111 = p11[x1];
            }
            float c00 = v000 + wx*(v001-v000);
            float c01 = v010 + wx*(v011-v010);
            float c10 = v100 + wx*(v101-v100);
            float c11 = v110 + wx*(v111-v110);
            float c0  = c00 + wy*(c01-c00);
            float c1  = c10 + wy*(c11-c10);
            res[jj]   = c0 + wz*(c1-c0);
        }
        f4v r = {res[0], res[1], res[2], res[3]};
        const size_t of4 = ((size_t)((b*BD + Z)*BH + Y)*BW + Xb) / 4;
        __builtin_nontemporal_store(r, &((f4v*)out)[of4]);
    }
}

extern "C" void kernel_launch(void* const* d_in, const int* in_sizes, int n_in,
                              void* d_out, int out_size, void* d_ws, size_t ws_size,
                              hipStream_t stream) {
    const float* vol = (const float*)d_in[0];
    const float* trf = (const float*)d_in[1];
    float* out = (float*)d_out;

    st_warp_kernel<<<dim3(NBLK), dim3(256), 0, stream>>>(vol, trf, out);
}